// Round 21
// baseline (89.655 us; speedup 1.0000x reference)
//
#include <hip/hip_runtime.h>
#include <hip/hip_bf16.h>

#define N_POS 4096
#define C_IN 64
#define IC 32
#define L2E 1.4426950408889634f

typedef float f32x16 __attribute__((ext_vector_type(16)));
typedef short bf16x8 __attribute__((ext_vector_type(8)));
typedef unsigned int uint;
typedef uint uint4v __attribute__((ext_vector_type(4)));
typedef unsigned short ushort;

static __device__ __forceinline__ ushort f2bf(float f) {
    __hip_bfloat16 h = __float2bfloat16(f);
    return __builtin_bit_cast(ushort, h);
}
static __device__ __forceinline__ uint packbf2(float lo, float hi) {
    return (uint)f2bf(lo) | ((uint)f2bf(hi) << 16);
}
// truncating pack in ONE v_perm_b32: D = [hi.b3, hi.b2, lo.b3, lo.b2]
static __device__ __forceinline__ uint packtrunc(float lo, float hi) {
    return __builtin_amdgcn_perm(__builtin_bit_cast(uint, hi),
                                 __builtin_bit_cast(uint, lo), 0x07060302u);
}

// ---------------- Stage A: projections -> bf16 MFMA layouts ----------------
// grid (256, 12): gy = proj*4 + q8. theta pre-scaled by log2(e).
// gy==0 blocks 0..63 also do mb prep (folded).
__global__ __launch_bounds__(128) void proj_kernel(
    const float* __restrict__ x,
    const float* __restrict__ g_w, const float* __restrict__ g_b,
    const float* __restrict__ th_w, const float* __restrict__ th_b,
    const float* __restrict__ ph_w, const float* __restrict__ ph_b,
    const float* __restrict__ mb,
    ushort* __restrict__ gcn, ushort* __restrict__ tht, ushort* __restrict__ pht,
    ushort* __restrict__ mbt, ushort* __restrict__ mbb)
{
    int gy = blockIdx.y;
    int pj = gy >> 2, q8 = gy & 3;     // projection, 8-channel quarter
    const float* wsrc = (pj == 0) ? g_w : (pj == 1) ? th_w : ph_w;
    const float* bsrc = (pj == 0) ? g_b : (pj == 1) ? th_b : ph_b;
    __shared__ float w[8][64];
    __shared__ float bias[8];
    int tid = threadIdx.x;
    for (int i = tid; i < 512; i += 128) w[i >> 6][i & 63] = wsrc[q8 * 512 + i];
    if (tid < 8) bias[tid] = bsrc[q8 * 8 + tid];
    __syncthreads();

    int ng = blockIdx.x * 128 + tid;
    int b = ng >> 12, n = ng & 4095;
    const float* xb = x + (size_t)b * C_IN * N_POS + n;
    float xr[64];
    #pragma unroll
    for (int c = 0; c < 64; c++) xr[c] = xb[(size_t)c * N_POS];

    float acc[8];
    #pragma unroll
    for (int o = 0; o < 8; o++) {
        float a = bias[o];
        const float4* w4 = (const float4*)w[o];
        #pragma unroll
        for (int c4 = 0; c4 < 16; c4++) {
            float4 wv = w4[c4];
            a += wv.x * xr[c4*4+0] + wv.y * xr[c4*4+1]
               + wv.z * xr[c4*4+2] + wv.w * xr[c4*4+3];
        }
        if (pj == 1) a *= L2E;
        acc[o] = a;
    }

    if (pj == 0) {
        #pragma unroll
        for (int c = 0; c < 8; c++)
            gcn[((size_t)(b * IC + q8 * 8 + c)) * N_POS + n] = f2bf(acc[c]);
    } else {
        ushort* dst = ((pj == 1) ? tht : pht) + ((size_t)(b * N_POS + n)) * IC + q8 * 8;
        uint4v pk;
        #pragma unroll
        for (int i = 0; i < 4; i++) pk[i] = packbf2(acc[2*i], acc[2*i+1]);
        *(uint4v*)dst = pk;
    }

    if (gy == 0 && blockIdx.x < 64) {
        int i = blockIdx.x * 128 + tid;
        int c = i >> 8, k = i & 255;
        float v = mb[i];
        mbb[i] = f2bf(v);
        mbt[k * 32 + c] = f2bf(v * (0.17677669529663687f * L2E));
    }
}

// ---- Fused: 16 waves (two q-pair groups jp=0,1) per 1024-thr block ---------
// block = (b, qq): each jp-half is the verified R19 8-wave pipeline for
// q-pair qq*2+jp. One resident block = 16 waves/CU = 4 waves/SIMD.
// Per-wave code byte-identical to R19 (124 regs, no spill at the 128 cap).
__global__ __launch_bounds__(1024) void attn_fused(
    const ushort* __restrict__ tht, const ushort* __restrict__ pht,
    const ushort* __restrict__ gcn, const ushort* __restrict__ mbt,
    const ushort* __restrict__ mbb, const float* __restrict__ x,
    const float* __restrict__ Ww, const float* __restrict__ Wb,
    const float* __restrict__ Wzw, const float* __restrict__ Wzb,
    float* __restrict__ out)
{
    __shared__ float redY[2][4][2][32][36];   // 72 KB
    __shared__ float redD[2][8][2][32];       // 4 KB
    __shared__ float ly1p[2][4][32][36];      // 36 KB
    __shared__ float sumeL[2][4][32];         // 1 KB   (total ~113.7 KB)

    int tid = threadIdx.x;
    int sg = tid >> 6;               // 0..15
    int jp = sg >> 3;                // q-pair half 0/1
    int s  = sg & 7;                 // wave within half
    int lane = tid & 63;
    int bid = blockIdx.x;
    int b = bid & 7;                 // batch -> XCD locality
    int qq = bid >> 3;               // 0..31
    int q0 = (qq * 2 + jp) * 64;
    int mbase = s * 512;
    int cl = lane & 31, h = lane >> 5;
    int t4 = (cl >> 2) & 3;
    int pcl = (t4 == 1 || t4 == 2) ? (cl ^ 12) : cl;   // pi row permutation

    const ushort* thpA = tht + ((size_t)(b * N_POS + q0 + cl)) * IC + 8 * h;
    bf16x8 thA0 = *(const bf16x8*)thpA;
    bf16x8 thA1 = *(const bf16x8*)(thpA + 16);
    const ushort* thpB = thpA + 32 * IC;
    bf16x8 thB0 = *(const bf16x8*)thpB;
    bf16x8 thB1 = *(const bf16x8*)(thpB + 16);

    const ushort* phbase = pht + (size_t)b * N_POS * IC;
    const ushort* gbase  = gcn + ((size_t)(b * IC + cl)) * N_POS;

    f32x16 yA, yB, zero;
    #pragma unroll
    for (int i = 0; i < 16; i++) { yA[i] = 0.f; yB[i] = 0.f; zero[i] = 0.f; }
    float sA0 = 0.f, sA1 = 0.f, sB0 = 0.f, sB1 = 0.f;

    #pragma unroll 2
    for (int mt = 0; mt < 16; ++mt) {
        int m0 = mbase + mt * 32;
        const ushort* php = phbase + ((size_t)(m0 + pcl)) * IC + 8 * h;
        bf16x8 ph0 = *(const bf16x8*)php;
        bf16x8 ph1 = *(const bf16x8*)(php + 16);
        const ushort* gp = gbase + m0 + 8 * h;
        bf16x8 g0 = *(const bf16x8*)gp;
        bf16x8 g1 = *(const bf16x8*)(gp + 16);

        f32x16 sv = __builtin_amdgcn_mfma_f32_32x32x16_bf16(ph0, thA0, zero, 0, 0, 0);
        sv = __builtin_amdgcn_mfma_f32_32x32x16_bf16(ph1, thA1, sv, 0, 0, 0);
        uint wA[8];
        #pragma unroll
        for (int i = 0; i < 8; i++) {
            float p0 = __builtin_amdgcn_exp2f(sv[2*i]);
            float p1 = __builtin_amdgcn_exp2f(sv[2*i+1]);
            if (i & 1) sA1 += p0 + p1; else sA0 += p0 + p1;
            wA[i] = packtrunc(p0, p1);
        }
        f32x16 sw = __builtin_amdgcn_mfma_f32_32x32x16_bf16(ph0, thB0, zero, 0, 0, 0);
        sw = __builtin_amdgcn_mfma_f32_32x32x16_bf16(ph1, thB1, sw, 0, 0, 0);
        uint wB[8];
        #pragma unroll
        for (int i = 0; i < 8; i++) {
            float p0 = __builtin_amdgcn_exp2f(sw[2*i]);
            float p1 = __builtin_amdgcn_exp2f(sw[2*i+1]);
            if (i & 1) sB1 += p0 + p1; else sB0 += p0 + p1;
            wB[i] = packtrunc(p0, p1);
        }

        uint4v aA0, aA1, aB0, aB1;
        aA0[0] = wA[0]; aA0[1] = wA[1]; aA0[2] = wA[2]; aA0[3] = wA[3];
        aA1[0] = wA[4]; aA1[1] = wA[5]; aA1[2] = wA[6]; aA1[3] = wA[7];
        aB0[0] = wB[0]; aB0[1] = wB[1]; aB0[2] = wB[2]; aB0[3] = wB[3];
        aB1[0] = wB[4]; aB1[1] = wB[5]; aB1[2] = wB[6]; aB1[3] = wB[7];

        yA = __builtin_amdgcn_mfma_f32_32x32x16_bf16(
            __builtin_bit_cast(bf16x8, aA0), g0, yA, 0, 0, 0);
        yB = __builtin_amdgcn_mfma_f32_32x32x16_bf16(
            __builtin_bit_cast(bf16x8, aB0), g0, yB, 0, 0, 0);
        yA = __builtin_amdgcn_mfma_f32_32x32x16_bf16(
            __builtin_bit_cast(bf16x8, aA1), g1, yA, 0, 0, 0);
        yB = __builtin_amdgcn_mfma_f32_32x32x16_bf16(
            __builtin_bit_cast(bf16x8, aB1), g1, yB, 0, 0, 0);
    }

    float sumeA = sA0 + sA1;
    float sumeB = sB0 + sB1;

    // W1: denominators (all waves); partial PV (waves 0-3 of each half write)
    sumeA += __shfl_xor(sumeA, 32);
    sumeB += __shfl_xor(sumeB, 32);
    if (lane < 32) { redD[jp][s][0][cl] = sumeA; redD[jp][s][1][cl] = sumeB; }
    if (s < 4) {
        #pragma unroll
        for (int r = 0; r < 16; r++) {
            int q = (r & 3) + 8 * (r >> 2) + 4 * h;
            redY[jp][s][0][q][cl] = yA[r];
            redY[jp][s][1][q][cl] = yB[r];
        }
    }
    __syncthreads();

    // W2: waves 4-7 accumulate; waves 0-3 do mb attention (reusing yA/yB)
    if (s >= 4) {
        int sl = s - 4;
        #pragma unroll
        for (int r = 0; r < 16; r++) {
            int q = (r & 3) + 8 * (r >> 2) + 4 * h;
            redY[jp][sl][0][q][cl] += yA[r];
            redY[jp][sl][1][q][cl] += yB[r];
        }
    } else {
        int j = s & 1, kh = s >> 1;
        int mq0 = q0 + j * 32;
        const ushort* php = pht + ((size_t)(b * N_POS + mq0 + cl)) * IC + 8 * h;
        bf16x8 qf0 = *(const bf16x8*)php;
        bf16x8 qf1 = *(const bf16x8*)(php + 16);

        yA = zero;   // reuse accumulators
        yB = zero;
        float su0 = 0.f, su1 = 0.f;

        #pragma unroll
        for (int kt = 0; kt < 4; ++kt) {
            int k0 = (kh * 4 + kt) * 32;
            const ushort* ap = mbt + ((size_t)(k0 + pcl)) * IC + 8 * h;
            bf16x8 af0 = *(const bf16x8*)ap;
            bf16x8 af1 = *(const bf16x8*)(ap + 16);
            const ushort* bp = mbb + (size_t)cl * 256 + k0 + 8 * h;
            bf16x8 bf0 = *(const bf16x8*)bp;
            bf16x8 bf1 = *(const bf16x8*)(bp + 16);

            f32x16 sv = __builtin_amdgcn_mfma_f32_32x32x16_bf16(af0, qf0, zero, 0, 0, 0);
            sv = __builtin_amdgcn_mfma_f32_32x32x16_bf16(af1, qf1, sv, 0, 0, 0);

            uint w[8];
            #pragma unroll
            for (int i = 0; i < 8; i++) {
                float p0 = __builtin_amdgcn_exp2f(sv[2*i]);
                float p1 = __builtin_amdgcn_exp2f(sv[2*i+1]);
                if (i & 1) su1 += p0 + p1; else su0 += p0 + p1;
                w[i] = packtrunc(p0, p1);
            }
            uint4v a0, a1;
            a0[0] = w[0]; a0[1] = w[1]; a0[2] = w[2]; a0[3] = w[3];
            a1[0] = w[4]; a1[1] = w[5]; a1[2] = w[6]; a1[3] = w[7];

            yA = __builtin_amdgcn_mfma_f32_32x32x16_bf16(
                __builtin_bit_cast(bf16x8, a0), bf0, yA, 0, 0, 0);
            yB = __builtin_amdgcn_mfma_f32_32x32x16_bf16(
                __builtin_bit_cast(bf16x8, a1), bf1, yB, 0, 0, 0);
        }

        float sume = su0 + su1;
        sume += __shfl_xor(sume, 32);
        if (lane < 32) sumeL[jp][s][cl] = sume;
        #pragma unroll
        for (int r = 0; r < 16; r++) {
            int q = (r & 3) + 8 * (r >> 2) + 4 * h;
            ly1p[jp][s][q][cl] = yA[r] + yB[r];
        }
    }
    __syncthreads();

    // W3: out matmul. wave s of half jp -> 8 outputs; lane -> n (coalesced).
    int nl = lane, og = s;
    int n = q0 + nl;
    int jo = nl >> 5, qo = nl & 31;

    float den = 0.f;
    #pragma unroll
    for (int s8 = 0; s8 < 8; s8++) den += redD[jp][s8][jo][qo];
    float inv = 1.f / den;
    float inv1 = 1.f / (sumeL[jp][jo][qo] + sumeL[jp][2 + jo][qo]);

    float yv[32], y1v[32];
    #pragma unroll
    for (int c4 = 0; c4 < 8; c4++) {
        float4 v0 = *(const float4*)&redY[jp][0][jo][qo][c4 * 4];
        float4 v1 = *(const float4*)&redY[jp][1][jo][qo][c4 * 4];
        float4 v2 = *(const float4*)&redY[jp][2][jo][qo][c4 * 4];
        float4 v3 = *(const float4*)&redY[jp][3][jo][qo][c4 * 4];
        yv[c4*4+0] = (v0.x + v1.x + v2.x + v3.x) * inv;
        yv[c4*4+1] = (v0.y + v1.y + v2.y + v3.y) * inv;
        yv[c4*4+2] = (v0.z + v1.z + v2.z + v3.z) * inv;
        yv[c4*4+3] = (v0.w + v1.w + v2.w + v3.w) * inv;
        float4 p0 = *(const float4*)&ly1p[jp][jo][qo][c4 * 4];
        float4 p1 = *(const float4*)&ly1p[jp][2 + jo][qo][c4 * 4];
        y1v[c4*4+0] = (p0.x + p1.x) * inv1;
        y1v[c4*4+1] = (p0.y + p1.y) * inv1;
        y1v[c4*4+2] = (p0.z + p1.z) * inv1;
        y1v[c4*4+3] = (p0.w + p1.w) * inv1;
    }

    int obase = og * 8;
    const float* xb = x   + ((size_t)(b * C_IN + obase)) * N_POS + n;
    float*       ob = out + ((size_t)(b * C_IN + obase)) * N_POS + n;
    #pragma unroll
    for (int o = 0; o < 8; o++) {
        float acc = Wb[obase + o] + Wzb[obase + o] + xb[(size_t)o * N_POS];
        const float4* w4  = (const float4*)(Ww  + (obase + o) * 32);
        const float4* wz4 = (const float4*)(Wzw + (obase + o) * 32);
        #pragma unroll
        for (int c4 = 0; c4 < 8; c4++) {
            float4 a = w4[c4], z = wz4[c4];
            acc += a.x * yv[c4*4+0] + a.y * yv[c4*4+1] + a.z * yv[c4*4+2] + a.w * yv[c4*4+3];
            acc += z.x * y1v[c4*4+0] + z.y * y1v[c4*4+1] + z.z * y1v[c4*4+2] + z.w * y1v[c4*4+3];
        }
        ob[(size_t)o * N_POS] = acc;
    }
}

extern "C" void kernel_launch(void* const* d_in, const int* in_sizes, int n_in,
                              void* d_out, int out_size, void* d_ws, size_t ws_size,
                              hipStream_t stream) {
    const float* x    = (const float*)d_in[0];
    const float* g_w  = (const float*)d_in[1];
    const float* g_b  = (const float*)d_in[2];
    const float* th_w = (const float*)d_in[3];
    const float* th_b = (const float*)d_in[4];
    const float* ph_w = (const float*)d_in[5];
    const float* ph_b = (const float*)d_in[6];
    const float* W_w  = (const float*)d_in[7];
    const float* W_b  = (const float*)d_in[8];
    const float* Wz_w = (const float*)d_in[9];
    const float* Wz_b = (const float*)d_in[10];
    const float* mb   = (const float*)d_in[11];
    float* out = (float*)d_out;

    char* w = (char*)d_ws;
    ushort* tht = (ushort*)w;                        // 2 MB
    ushort* pht = (ushort*)(w + (2u << 20));         // 2 MB
    ushort* gcn = (ushort*)(w + (4u << 20));         // 2 MB
    ushort* mbt = (ushort*)(w + (6u << 20));         // 16 KB
    ushort* mbb = (ushort*)(w + (6u << 20) + 16384); // 16 KB

    proj_kernel<<<dim3(256, 12), 128, 0, stream>>>(x, g_w, g_b, th_w, th_b,
                                                   ph_w, ph_b, mb,
                                                   gcn, tht, pht, mbt, mbb);
    attn_fused<<<256, 1024, 0, stream>>>(tht, pht, gcn, mbt, mbb, x,
                                         W_w, W_b, Wz_w, Wz_b, out);
}

// Round 22
// 83.414 us; speedup vs baseline: 1.0748x; 1.0748x over previous
//
#include <hip/hip_runtime.h>
#include <hip/hip_bf16.h>

#define N_POS 4096
#define C_IN 64
#define IC 32
#define L2E 1.4426950408889634f

typedef float f32x16 __attribute__((ext_vector_type(16)));
typedef short bf16x8 __attribute__((ext_vector_type(8)));
typedef unsigned int uint;
typedef uint uint4v __attribute__((ext_vector_type(4)));
typedef unsigned short ushort;

static __device__ __forceinline__ ushort f2bf(float f) {
    __hip_bfloat16 h = __float2bfloat16(f);
    return __builtin_bit_cast(ushort, h);
}
static __device__ __forceinline__ uint packbf2(float lo, float hi) {
    return (uint)f2bf(lo) | ((uint)f2bf(hi) << 16);
}
// truncating pack in ONE v_perm_b32: D = [hi.b3, hi.b2, lo.b3, lo.b2]
static __device__ __forceinline__ uint packtrunc(float lo, float hi) {
    return __builtin_amdgcn_perm(__builtin_bit_cast(uint, hi),
                                 __builtin_bit_cast(uint, lo), 0x07060302u);
}

// ---------------- Stage A: projections, K-split x4 --------------------------
// grid (512, 2) x 256 thr = 4096 waves (4/SIMD). blockIdx.y = half:
// channels half*16..+15 of ALL THREE projections (48 outputs).
// Thread = (position, K-quarter): 16 loads + 48x16 FMA, 2-step shfl reduce.
// theta pre-scaled by log2(e). half==0 blocks 0..63 also do mb prep.
__global__ __launch_bounds__(256) void proj_kernel(
    const float* __restrict__ x,
    const float* __restrict__ g_w, const float* __restrict__ g_b,
    const float* __restrict__ th_w, const float* __restrict__ th_b,
    const float* __restrict__ ph_w, const float* __restrict__ ph_b,
    const float* __restrict__ mb,
    ushort* __restrict__ gcn, ushort* __restrict__ tht, ushort* __restrict__ pht,
    ushort* __restrict__ mbt, ushort* __restrict__ mbb)
{
    int half = blockIdx.y;
    __shared__ float w[48][64];    // rows 0-15 g, 16-31 theta(*L2E), 32-47 phi
    __shared__ float bias[48];
    int tid = threadIdx.x;
    for (int i = tid; i < 3072; i += 256) {
        int r = i >> 6, c = i & 63;
        const float* src = (r < 16) ? g_w : (r < 32) ? th_w : ph_w;
        float v = src[((r & 15) + half * 16) * 64 + c];
        if (r >= 16 && r < 32) v *= L2E;
        w[r][c] = v;
    }
    if (tid < 48) {
        const float* bsrc = (tid < 16) ? g_b : (tid < 32) ? th_b : ph_b;
        float v = bsrc[(tid & 15) + half * 16];
        if (tid >= 16 && tid < 32) v *= L2E;
        bias[tid] = v;
    }
    __syncthreads();

    int ks = tid & 3;                      // K-quarter: channels ks*16..+15
    int pos = blockIdx.x * 64 + (tid >> 2);
    int b = pos >> 12, n = pos & 4095;
    const float* xb = x + ((size_t)(b * C_IN + ks * 16)) * N_POS + n;
    float xr[16];
    #pragma unroll
    for (int c = 0; c < 16; c++) xr[c] = xb[(size_t)c * N_POS];

    float acc[48];
    #pragma unroll
    for (int o = 0; o < 48; o++) {
        float a = 0.f;
        const float4* w4 = (const float4*)&w[o][ks * 16];
        #pragma unroll
        for (int c4 = 0; c4 < 4; c4++) {
            float4 wv = w4[c4];
            a += wv.x * xr[c4*4+0] + wv.y * xr[c4*4+1]
               + wv.z * xr[c4*4+2] + wv.w * xr[c4*4+3];
        }
        acc[o] = a;
    }
    // combine the 4 K-quarters (lanes tid^1, tid^2 within the same wave)
    #pragma unroll
    for (int o = 0; o < 48; o++) {
        acc[o] += __shfl_xor(acc[o], 1);
        acc[o] += __shfl_xor(acc[o], 2);
    }

    if (ks == 0) {
        #pragma unroll
        for (int c = 0; c < 16; c++)
            gcn[((size_t)(b * IC + half * 16 + c)) * N_POS + n] =
                f2bf(acc[c] + bias[c]);
        {
            ushort* dst = tht + ((size_t)(b * N_POS + n)) * IC + half * 16;
            uint4v pk0, pk1;
            #pragma unroll
            for (int i = 0; i < 4; i++)
                pk0[i] = packbf2(acc[16 + 2*i] + bias[16 + 2*i],
                                 acc[17 + 2*i] + bias[17 + 2*i]);
            #pragma unroll
            for (int i = 0; i < 4; i++)
                pk1[i] = packbf2(acc[24 + 2*i] + bias[24 + 2*i],
                                 acc[25 + 2*i] + bias[25 + 2*i]);
            *(uint4v*)dst = pk0;
            *(uint4v*)(dst + 8) = pk1;
        }
        {
            ushort* dst = pht + ((size_t)(b * N_POS + n)) * IC + half * 16;
            uint4v pk0, pk1;
            #pragma unroll
            for (int i = 0; i < 4; i++)
                pk0[i] = packbf2(acc[32 + 2*i] + bias[32 + 2*i],
                                 acc[33 + 2*i] + bias[33 + 2*i]);
            #pragma unroll
            for (int i = 0; i < 4; i++)
                pk1[i] = packbf2(acc[40 + 2*i] + bias[40 + 2*i],
                                 acc[41 + 2*i] + bias[41 + 2*i]);
            *(uint4v*)dst = pk0;
            *(uint4v*)(dst + 8) = pk1;
        }
    }

    // folded mb prep: 64 blocks x 128 threads = 8192 elements
    if (half == 0 && blockIdx.x < 64 && tid < 128) {
        int i = blockIdx.x * 128 + tid;
        int c = i >> 8, k = i & 255;
        float v = mb[i];
        mbb[i] = f2bf(v);
        mbt[k * 32 + c] = f2bf(v * (0.17677669529663687f * L2E));
    }
}

// ---- Fused: non-local attn (8 waves x 512 keys) + mb attn + out matmul -----
// Byte-identical to R19 (best passing: 53.0-53.2 us).
__global__ __launch_bounds__(512) void attn_fused(
    const ushort* __restrict__ tht, const ushort* __restrict__ pht,
    const ushort* __restrict__ gcn, const ushort* __restrict__ mbt,
    const ushort* __restrict__ mbb, const float* __restrict__ x,
    const float* __restrict__ Ww, const float* __restrict__ Wb,
    const float* __restrict__ Wzw, const float* __restrict__ Wzb,
    float* __restrict__ out)
{
    __shared__ float redY[4][2][32][36];   // 36 KB, 144B rows (16B-aligned)
    __shared__ float redD[8][2][32];       // 2 KB
    __shared__ float ly1p[4][32][36];      // 18 KB
    __shared__ float sumeL[4][32];         // 0.5 KB

    int tid = threadIdx.x;
    int s = tid >> 6, lane = tid & 63;
    int bid = blockIdx.x;
    int b = bid & 7;                 // batch -> XCD locality
    int qp = bid >> 3;               // 0..63
    int q0 = qp * 64;
    int mbase = s * 512;
    int cl = lane & 31, h = lane >> 5;
    int t4 = (cl >> 2) & 3;
    int pcl = (t4 == 1 || t4 == 2) ? (cl ^ 12) : cl;   // pi row permutation

    const ushort* thpA = tht + ((size_t)(b * N_POS + q0 + cl)) * IC + 8 * h;
    bf16x8 thA0 = *(const bf16x8*)thpA;
    bf16x8 thA1 = *(const bf16x8*)(thpA + 16);
    const ushort* thpB = thpA + 32 * IC;
    bf16x8 thB0 = *(const bf16x8*)thpB;
    bf16x8 thB1 = *(const bf16x8*)(thpB + 16);

    const ushort* phbase = pht + (size_t)b * N_POS * IC;
    const ushort* gbase  = gcn + ((size_t)(b * IC + cl)) * N_POS;

    f32x16 yA, yB, zero;
    #pragma unroll
    for (int i = 0; i < 16; i++) { yA[i] = 0.f; yB[i] = 0.f; zero[i] = 0.f; }
    float sA0 = 0.f, sA1 = 0.f, sB0 = 0.f, sB1 = 0.f;

    #pragma unroll 2
    for (int mt = 0; mt < 16; ++mt) {
        int m0 = mbase + mt * 32;
        const ushort* php = phbase + ((size_t)(m0 + pcl)) * IC + 8 * h;
        bf16x8 ph0 = *(const bf16x8*)php;
        bf16x8 ph1 = *(const bf16x8*)(php + 16);
        const ushort* gp = gbase + m0 + 8 * h;
        bf16x8 g0 = *(const bf16x8*)gp;
        bf16x8 g1 = *(const bf16x8*)(gp + 16);

        f32x16 sv = __builtin_amdgcn_mfma_f32_32x32x16_bf16(ph0, thA0, zero, 0, 0, 0);
        sv = __builtin_amdgcn_mfma_f32_32x32x16_bf16(ph1, thA1, sv, 0, 0, 0);
        uint wA[8];
        #pragma unroll
        for (int i = 0; i < 8; i++) {
            float p0 = __builtin_amdgcn_exp2f(sv[2*i]);
            float p1 = __builtin_amdgcn_exp2f(sv[2*i+1]);
            if (i & 1) sA1 += p0 + p1; else sA0 += p0 + p1;
            wA[i] = packtrunc(p0, p1);
        }
        f32x16 sw = __builtin_amdgcn_mfma_f32_32x32x16_bf16(ph0, thB0, zero, 0, 0, 0);
        sw = __builtin_amdgcn_mfma_f32_32x32x16_bf16(ph1, thB1, sw, 0, 0, 0);
        uint wB[8];
        #pragma unroll
        for (int i = 0; i < 8; i++) {
            float p0 = __builtin_amdgcn_exp2f(sw[2*i]);
            float p1 = __builtin_amdgcn_exp2f(sw[2*i+1]);
            if (i & 1) sB1 += p0 + p1; else sB0 += p0 + p1;
            wB[i] = packtrunc(p0, p1);
        }

        uint4v aA0, aA1, aB0, aB1;
        aA0[0] = wA[0]; aA0[1] = wA[1]; aA0[2] = wA[2]; aA0[3] = wA[3];
        aA1[0] = wA[4]; aA1[1] = wA[5]; aA1[2] = wA[6]; aA1[3] = wA[7];
        aB0[0] = wB[0]; aB0[1] = wB[1]; aB0[2] = wB[2]; aB0[3] = wB[3];
        aB1[0] = wB[4]; aB1[1] = wB[5]; aB1[2] = wB[6]; aB1[3] = wB[7];

        yA = __builtin_amdgcn_mfma_f32_32x32x16_bf16(
            __builtin_bit_cast(bf16x8, aA0), g0, yA, 0, 0, 0);
        yB = __builtin_amdgcn_mfma_f32_32x32x16_bf16(
            __builtin_bit_cast(bf16x8, aB0), g0, yB, 0, 0, 0);
        yA = __builtin_amdgcn_mfma_f32_32x32x16_bf16(
            __builtin_bit_cast(bf16x8, aA1), g1, yA, 0, 0, 0);
        yB = __builtin_amdgcn_mfma_f32_32x32x16_bf16(
            __builtin_bit_cast(bf16x8, aB1), g1, yB, 0, 0, 0);
    }

    float sumeA = sA0 + sA1;
    float sumeB = sB0 + sB1;

    // W1: denominators (all waves); partial PV (waves 0-3 write)
    sumeA += __shfl_xor(sumeA, 32);
    sumeB += __shfl_xor(sumeB, 32);
    if (lane < 32) { redD[s][0][cl] = sumeA; redD[s][1][cl] = sumeB; }
    if (s < 4) {
        #pragma unroll
        for (int r = 0; r < 16; r++) {
            int q = (r & 3) + 8 * (r >> 2) + 4 * h;
            redY[s][0][q][cl] = yA[r];
            redY[s][1][q][cl] = yB[r];
        }
    }
    __syncthreads();

    // W2: waves 4-7 accumulate (single writer per slot); waves 0-3 do mb attn
    if (s >= 4) {
        int sl = s - 4;
        #pragma unroll
        for (int r = 0; r < 16; r++) {
            int q = (r & 3) + 8 * (r >> 2) + 4 * h;
            redY[sl][0][q][cl] += yA[r];
            redY[sl][1][q][cl] += yB[r];
        }
    } else {
        int j = s & 1, kh = s >> 1;
        int mq0 = q0 + j * 32;
        const ushort* php = pht + ((size_t)(b * N_POS + mq0 + cl)) * IC + 8 * h;
        bf16x8 qf0 = *(const bf16x8*)php;
        bf16x8 qf1 = *(const bf16x8*)(php + 16);

        yA = zero;   // reuse accumulators
        yB = zero;
        float su0 = 0.f, su1 = 0.f;

        #pragma unroll
        for (int kt = 0; kt < 4; ++kt) {
            int k0 = (kh * 4 + kt) * 32;
            const ushort* ap = mbt + ((size_t)(k0 + pcl)) * IC + 8 * h;
            bf16x8 af0 = *(const bf16x8*)ap;
            bf16x8 af1 = *(const bf16x8*)(ap + 16);
            const ushort* bp = mbb + (size_t)cl * 256 + k0 + 8 * h;
            bf16x8 bf0 = *(const bf16x8*)bp;
            bf16x8 bf1 = *(const bf16x8*)(bp + 16);

            f32x16 sv = __builtin_amdgcn_mfma_f32_32x32x16_bf16(af0, qf0, zero, 0, 0, 0);
            sv = __builtin_amdgcn_mfma_f32_32x32x16_bf16(af1, qf1, sv, 0, 0, 0);

            uint w[8];
            #pragma unroll
            for (int i = 0; i < 8; i++) {
                float p0 = __builtin_amdgcn_exp2f(sv[2*i]);
                float p1 = __builtin_amdgcn_exp2f(sv[2*i+1]);
                if (i & 1) su1 += p0 + p1; else su0 += p0 + p1;
                w[i] = packtrunc(p0, p1);
            }
            uint4v a0, a1;
            a0[0] = w[0]; a0[1] = w[1]; a0[2] = w[2]; a0[3] = w[3];
            a1[0] = w[4]; a1[1] = w[5]; a1[2] = w[6]; a1[3] = w[7];

            yA = __builtin_amdgcn_mfma_f32_32x32x16_bf16(
                __builtin_bit_cast(bf16x8, a0), bf0, yA, 0, 0, 0);
            yB = __builtin_amdgcn_mfma_f32_32x32x16_bf16(
                __builtin_bit_cast(bf16x8, a1), bf1, yB, 0, 0, 0);
        }

        float sume = su0 + su1;
        sume += __shfl_xor(sume, 32);
        if (lane < 32) sumeL[s][cl] = sume;
        #pragma unroll
        for (int r = 0; r < 16; r++) {
            int q = (r & 3) + 8 * (r >> 2) + 4 * h;
            ly1p[s][q][cl] = yA[r] + yB[r];
        }
    }
    __syncthreads();

    // W3: out matmul. thread = (og = wave, nl = lane); n coalesced.
    int nl = lane, og = s;
    int n = q0 + nl;
    int jo = nl >> 5, qo = nl & 31;

    float den = 0.f;
    #pragma unroll
    for (int s8 = 0; s8 < 8; s8++) den += redD[s8][jo][qo];
    float inv = 1.f / den;
    float inv1 = 1.f / (sumeL[jo][qo] + sumeL[2 + jo][qo]);

    float yv[32], y1v[32];
    #pragma unroll
    for (int c4 = 0; c4 < 8; c4++) {
        float4 v0 = *(const float4*)&redY[0][jo][qo][c4 * 4];
        float4 v1 = *(const float4*)&redY[1][jo][qo][c4 * 4];
        float4 v2 = *(const float4*)&redY[2][jo][qo][c4 * 4];
        float4 v3 = *(const float4*)&redY[3][jo][qo][c4 * 4];
        yv[c4*4+0] = (v0.x + v1.x + v2.x + v3.x) * inv;
        yv[c4*4+1] = (v0.y + v1.y + v2.y + v3.y) * inv;
        yv[c4*4+2] = (v0.z + v1.z + v2.z + v3.z) * inv;
        yv[c4*4+3] = (v0.w + v1.w + v2.w + v3.w) * inv;
        float4 p0 = *(const float4*)&ly1p[jo][qo][c4 * 4];
        float4 p1 = *(const float4*)&ly1p[2 + jo][qo][c4 * 4];
        y1v[c4*4+0] = (p0.x + p1.x) * inv1;
        y1v[c4*4+1] = (p0.y + p1.y) * inv1;
        y1v[c4*4+2] = (p0.z + p1.z) * inv1;
        y1v[c4*4+3] = (p0.w + p1.w) * inv1;
    }

    int obase = og * 8;
    const float* xb = x   + ((size_t)(b * C_IN + obase)) * N_POS + n;
    float*       ob = out + ((size_t)(b * C_IN + obase)) * N_POS + n;
    #pragma unroll
    for (int o = 0; o < 8; o++) {
        float acc = Wb[obase + o] + Wzb[obase + o] + xb[(size_t)o * N_POS];
        const float4* w4  = (const float4*)(Ww  + (obase + o) * 32);
        const float4* wz4 = (const float4*)(Wzw + (obase + o) * 32);
        #pragma unroll
        for (int c4 = 0; c4 < 8; c4++) {
            float4 a = w4[c4], z = wz4[c4];
            acc += a.x * yv[c4*4+0] + a.y * yv[c4*4+1] + a.z * yv[c4*4+2] + a.w * yv[c4*4+3];
            acc += z.x * y1v[c4*4+0] + z.y * y1v[c4*4+1] + z.z * y1v[c4*4+2] + z.w * y1v[c4*4+3];
        }
        ob[(size_t)o * N_POS] = acc;
    }
}

extern "C" void kernel_launch(void* const* d_in, const int* in_sizes, int n_in,
                              void* d_out, int out_size, void* d_ws, size_t ws_size,
                              hipStream_t stream) {
    const float* x    = (const float*)d_in[0];
    const float* g_w  = (const float*)d_in[1];
    const float* g_b  = (const float*)d_in[2];
    const float* th_w = (const float*)d_in[3];
    const float* th_b = (const float*)d_in[4];
    const float* ph_w = (const float*)d_in[5];
    const float* ph_b = (const float*)d_in[6];
    const float* W_w  = (const float*)d_in[7];
    const float* W_b  = (const float*)d_in[8];
    const float* Wz_w = (const float*)d_in[9];
    const float* Wz_b = (const float*)d_in[10];
    const float* mb   = (const float*)d_in[11];
    float* out = (float*)d_out;

    char* w = (char*)d_ws;
    ushort* tht = (ushort*)w;                        // 2 MB
    ushort* pht = (ushort*)(w + (2u << 20));         // 2 MB
    ushort* gcn = (ushort*)(w + (4u << 20));         // 2 MB
    ushort* mbt = (ushort*)(w + (6u << 20));         // 16 KB
    ushort* mbb = (ushort*)(w + (6u << 20) + 16384); // 16 KB

    proj_kernel<<<dim3(512, 2), 256, 0, stream>>>(x, g_w, g_b, th_w, th_b,
                                                  ph_w, ph_b, mb,
                                                  gcn, tht, pht, mbt, mbb);
    attn_fused<<<512, 512, 0, stream>>>(tht, pht, gcn, mbt, mbb, x,
                                        W_w, W_b, Wz_w, Wz_b, out);
}

// Round 23
// 73.200 us; speedup vs baseline: 1.2248x; 1.1395x over previous
//
#include <hip/hip_runtime.h>
#include <hip/hip_bf16.h>

#define N_POS 4096
#define C_IN 64
#define IC 32
#define L2E 1.4426950408889634f

typedef float f32x16 __attribute__((ext_vector_type(16)));
typedef short bf16x8 __attribute__((ext_vector_type(8)));
typedef unsigned int uint;
typedef uint uint4v __attribute__((ext_vector_type(4)));
typedef unsigned short ushort;

static __device__ __forceinline__ ushort f2bf(float f) {
    __hip_bfloat16 h = __float2bfloat16(f);
    return __builtin_bit_cast(ushort, h);
}
static __device__ __forceinline__ uint packbf2(float lo, float hi) {
    return (uint)f2bf(lo) | ((uint)f2bf(hi) << 16);
}
// truncating pack in ONE v_perm_b32: D = [hi.b3, hi.b2, lo.b3, lo.b2]
static __device__ __forceinline__ uint packtrunc(float lo, float hi) {
    return __builtin_amdgcn_perm(__builtin_bit_cast(uint, hi),
                                 __builtin_bit_cast(uint, lo), 0x07060302u);
}

// ---------------- Stage A: projections -> bf16 MFMA layouts ----------------
// grid (256, 12): gy = proj*4 + q8 (8 output channels per block -> 6 waves/SIMD).
// theta pre-scaled by log2(e). gy==0 blocks 0..63 also do mb prep (folded).
__global__ __launch_bounds__(128) void proj_kernel(
    const float* __restrict__ x,
    const float* __restrict__ g_w, const float* __restrict__ g_b,
    const float* __restrict__ th_w, const float* __restrict__ th_b,
    const float* __restrict__ ph_w, const float* __restrict__ ph_b,
    const float* __restrict__ mb,
    ushort* __restrict__ gcn, ushort* __restrict__ tht, ushort* __restrict__ pht,
    ushort* __restrict__ mbt, ushort* __restrict__ mbb)
{
    int gy = blockIdx.y;
    int pj = gy >> 2, q8 = gy & 3;     // projection, 8-channel quarter
    const float* wsrc = (pj == 0) ? g_w : (pj == 1) ? th_w : ph_w;
    const float* bsrc = (pj == 0) ? g_b : (pj == 1) ? th_b : ph_b;
    __shared__ float w[8][64];
    __shared__ float bias[8];
    int tid = threadIdx.x;
    for (int i = tid; i < 512; i += 128) w[i >> 6][i & 63] = wsrc[q8 * 512 + i];
    if (tid < 8) bias[tid] = bsrc[q8 * 8 + tid];
    __syncthreads();

    int ng = blockIdx.x * 128 + tid;
    int b = ng >> 12, n = ng & 4095;
    const float* xb = x + (size_t)b * C_IN * N_POS + n;
    float xr[64];
    #pragma unroll
    for (int c = 0; c < 64; c++) xr[c] = xb[(size_t)c * N_POS];

    float acc[8];
    #pragma unroll
    for (int o = 0; o < 8; o++) {
        float a = bias[o];
        const float4* w4 = (const float4*)w[o];
        #pragma unroll
        for (int c4 = 0; c4 < 16; c4++) {
            float4 wv = w4[c4];
            a += wv.x * xr[c4*4+0] + wv.y * xr[c4*4+1]
               + wv.z * xr[c4*4+2] + wv.w * xr[c4*4+3];
        }
        if (pj == 1) a *= L2E;
        acc[o] = a;
    }

    if (pj == 0) {
        #pragma unroll
        for (int c = 0; c < 8; c++)
            gcn[((size_t)(b * IC + q8 * 8 + c)) * N_POS + n] = f2bf(acc[c]);
    } else {
        ushort* dst = ((pj == 1) ? tht : pht) + ((size_t)(b * N_POS + n)) * IC + q8 * 8;
        uint4v pk;
        #pragma unroll
        for (int i = 0; i < 4; i++) pk[i] = packbf2(acc[2*i], acc[2*i+1]);
        *(uint4v*)dst = pk;
    }

    if (gy == 0 && blockIdx.x < 64) {
        int i = blockIdx.x * 128 + tid;
        int c = i >> 8, k = i & 255;
        float v = mb[i];
        mbb[i] = f2bf(v);
        mbt[k * 32 + c] = f2bf(v * (0.17677669529663687f * L2E));
    }
}

// ---- Fused: non-local attn (8 waves x 512 keys) + mb attn + out matmul -----
// block = (b, qpair): 512 thr. W1: waves 0-3 write redY; W2: waves 4-7 add
// (one writer/slot) while waves 0-3 run mb attention; W3: out matmul.
// sume uses 2 interleaved accumulators to halve the serial add chain.
__global__ __launch_bounds__(512) void attn_fused(
    const ushort* __restrict__ tht, const ushort* __restrict__ pht,
    const ushort* __restrict__ gcn, const ushort* __restrict__ mbt,
    const ushort* __restrict__ mbb, const float* __restrict__ x,
    const float* __restrict__ Ww, const float* __restrict__ Wb,
    const float* __restrict__ Wzw, const float* __restrict__ Wzb,
    float* __restrict__ out)
{
    __shared__ float redY[4][2][32][36];   // 36 KB, 144B rows (16B-aligned)
    __shared__ float redD[8][2][32];       // 2 KB
    __shared__ float ly1p[4][32][36];      // 18 KB
    __shared__ float sumeL[4][32];         // 0.5 KB

    int tid = threadIdx.x;
    int s = tid >> 6, lane = tid & 63;
    int bid = blockIdx.x;
    int b = bid & 7;                 // batch -> XCD locality
    int qp = bid >> 3;               // 0..63
    int q0 = qp * 64;
    int mbase = s * 512;
    int cl = lane & 31, h = lane >> 5;
    int t4 = (cl >> 2) & 3;
    int pcl = (t4 == 1 || t4 == 2) ? (cl ^ 12) : cl;   // pi row permutation

    const ushort* thpA = tht + ((size_t)(b * N_POS + q0 + cl)) * IC + 8 * h;
    bf16x8 thA0 = *(const bf16x8*)thpA;
    bf16x8 thA1 = *(const bf16x8*)(thpA + 16);
    const ushort* thpB = thpA + 32 * IC;
    bf16x8 thB0 = *(const bf16x8*)thpB;
    bf16x8 thB1 = *(const bf16x8*)(thpB + 16);

    const ushort* phbase = pht + (size_t)b * N_POS * IC;
    const ushort* gbase  = gcn + ((size_t)(b * IC + cl)) * N_POS;

    f32x16 yA0, yA1, yB0, yB1, zero;
    #pragma unroll
    for (int i = 0; i < 16; i++) {
        yA0[i] = 0.f; yA1[i] = 0.f; yB0[i] = 0.f; yB1[i] = 0.f; zero[i] = 0.f;
    }
    float sA0 = 0.f, sA1 = 0.f, sB0 = 0.f, sB1 = 0.f;

    #pragma unroll 2
    for (int mt = 0; mt < 16; ++mt) {
        int m0 = mbase + mt * 32;
        const ushort* php = phbase + ((size_t)(m0 + pcl)) * IC + 8 * h;
        bf16x8 ph0 = *(const bf16x8*)php;
        bf16x8 ph1 = *(const bf16x8*)(php + 16);
        const ushort* gp = gbase + m0 + 8 * h;
        bf16x8 g0 = *(const bf16x8*)gp;
        bf16x8 g1 = *(const bf16x8*)(gp + 16);

        f32x16 sv = __builtin_amdgcn_mfma_f32_32x32x16_bf16(ph0, thA0, zero, 0, 0, 0);
        sv = __builtin_amdgcn_mfma_f32_32x32x16_bf16(ph1, thA1, sv, 0, 0, 0);
        uint wA[8];
        #pragma unroll
        for (int i = 0; i < 8; i++) {
            float p0 = __builtin_amdgcn_exp2f(sv[2*i]);
            float p1 = __builtin_amdgcn_exp2f(sv[2*i+1]);
            if (i & 1) sA1 += p0 + p1; else sA0 += p0 + p1;
            wA[i] = packtrunc(p0, p1);
        }
        f32x16 sw = __builtin_amdgcn_mfma_f32_32x32x16_bf16(ph0, thB0, zero, 0, 0, 0);
        sw = __builtin_amdgcn_mfma_f32_32x32x16_bf16(ph1, thB1, sw, 0, 0, 0);
        uint wB[8];
        #pragma unroll
        for (int i = 0; i < 8; i++) {
            float p0 = __builtin_amdgcn_exp2f(sw[2*i]);
            float p1 = __builtin_amdgcn_exp2f(sw[2*i+1]);
            if (i & 1) sB1 += p0 + p1; else sB0 += p0 + p1;
            wB[i] = packtrunc(p0, p1);
        }

        uint4v aA0, aA1, aB0, aB1;
        aA0[0] = wA[0]; aA0[1] = wA[1]; aA0[2] = wA[2]; aA0[3] = wA[3];
        aA1[0] = wA[4]; aA1[1] = wA[5]; aA1[2] = wA[6]; aA1[3] = wA[7];
        aB0[0] = wB[0]; aB0[1] = wB[1]; aB0[2] = wB[2]; aB0[3] = wB[3];
        aB1[0] = wB[4]; aB1[1] = wB[5]; aB1[2] = wB[6]; aB1[3] = wB[7];

        yA0 = __builtin_amdgcn_mfma_f32_32x32x16_bf16(
            __builtin_bit_cast(bf16x8, aA0), g0, yA0, 0, 0, 0);
        yA1 = __builtin_amdgcn_mfma_f32_32x32x16_bf16(
            __builtin_bit_cast(bf16x8, aA1), g1, yA1, 0, 0, 0);
        yB0 = __builtin_amdgcn_mfma_f32_32x32x16_bf16(
            __builtin_bit_cast(bf16x8, aB0), g0, yB0, 0, 0, 0);
        yB1 = __builtin_amdgcn_mfma_f32_32x32x16_bf16(
            __builtin_bit_cast(bf16x8, aB1), g1, yB1, 0, 0, 0);
    }

    float sumeA = sA0 + sA1;
    float sumeB = sB0 + sB1;

    // W1: denominators (all waves); partial PV (waves 0-3 write)
    sumeA += __shfl_xor(sumeA, 32);
    sumeB += __shfl_xor(sumeB, 32);
    if (lane < 32) { redD[s][0][cl] = sumeA; redD[s][1][cl] = sumeB; }
    if (s < 4) {
        #pragma unroll
        for (int r = 0; r < 16; r++) {
            int q = (r & 3) + 8 * (r >> 2) + 4 * h;
            redY[s][0][q][cl] = yA0[r] + yA1[r];
            redY[s][1][q][cl] = yB0[r] + yB1[r];
        }
    }
    __syncthreads();

    // W2: waves 4-7 accumulate (single writer per slot); waves 0-3 do mb attn
    if (s >= 4) {
        int sl = s - 4;
        #pragma unroll
        for (int r = 0; r < 16; r++) {
            int q = (r & 3) + 8 * (r >> 2) + 4 * h;
            redY[sl][0][q][cl] += yA0[r] + yA1[r];
            redY[sl][1][q][cl] += yB0[r] + yB1[r];
        }
    } else {
        int j = s & 1, kh = s >> 1;
        int mq0 = q0 + j * 32;
        const ushort* php = pht + ((size_t)(b * N_POS + mq0 + cl)) * IC + 8 * h;
        bf16x8 qf0 = *(const bf16x8*)php;
        bf16x8 qf1 = *(const bf16x8*)(php + 16);

        f32x16 zA, zB;
        #pragma unroll
        for (int i = 0; i < 16; i++) { zA[i] = 0.f; zB[i] = 0.f; }
        float su0 = 0.f, su1 = 0.f;

        #pragma unroll
        for (int kt = 0; kt < 4; ++kt) {
            int k0 = (kh * 4 + kt) * 32;
            const ushort* ap = mbt + ((size_t)(k0 + pcl)) * IC + 8 * h;
            bf16x8 af0 = *(const bf16x8*)ap;
            bf16x8 af1 = *(const bf16x8*)(ap + 16);
            const ushort* bp = mbb + (size_t)cl * 256 + k0 + 8 * h;
            bf16x8 bf0 = *(const bf16x8*)bp;
            bf16x8 bf1 = *(const bf16x8*)(bp + 16);

            f32x16 sv = __builtin_amdgcn_mfma_f32_32x32x16_bf16(af0, qf0, zero, 0, 0, 0);
            sv = __builtin_amdgcn_mfma_f32_32x32x16_bf16(af1, qf1, sv, 0, 0, 0);

            uint w[8];
            #pragma unroll
            for (int i = 0; i < 8; i++) {
                float p0 = __builtin_amdgcn_exp2f(sv[2*i]);
                float p1 = __builtin_amdgcn_exp2f(sv[2*i+1]);
                if (i & 1) su1 += p0 + p1; else su0 += p0 + p1;
                w[i] = packtrunc(p0, p1);
            }
            uint4v a0, a1;
            a0[0] = w[0]; a0[1] = w[1]; a0[2] = w[2]; a0[3] = w[3];
            a1[0] = w[4]; a1[1] = w[5]; a1[2] = w[6]; a1[3] = w[7];

            zA = __builtin_amdgcn_mfma_f32_32x32x16_bf16(
                __builtin_bit_cast(bf16x8, a0), bf0, zA, 0, 0, 0);
            zB = __builtin_amdgcn_mfma_f32_32x32x16_bf16(
                __builtin_bit_cast(bf16x8, a1), bf1, zB, 0, 0, 0);
        }

        float sume = su0 + su1;
        sume += __shfl_xor(sume, 32);
        if (lane < 32) sumeL[s][cl] = sume;
        #pragma unroll
        for (int r = 0; r < 16; r++) {
            int q = (r & 3) + 8 * (r >> 2) + 4 * h;
            ly1p[s][q][cl] = zA[r] + zB[r];
        }
    }
    __syncthreads();

    // W3: out matmul. thread = (og = wave, nl = lane); n coalesced.
    int nl = lane, og = s;
    int n = q0 + nl;
    int jo = nl >> 5, qo = nl & 31;

    float den = 0.f;
    #pragma unroll
    for (int s8 = 0; s8 < 8; s8++) den += redD[s8][jo][qo];
    float inv = 1.f / den;
    float inv1 = 1.f / (sumeL[jo][qo] + sumeL[2 + jo][qo]);

    float yv[32], y1v[32];
    #pragma unroll
    for (int c4 = 0; c4 < 8; c4++) {
        float4 v0 = *(const float4*)&redY[0][jo][qo][c4 * 4];
        float4 v1 = *(const float4*)&redY[1][jo][qo][c4 * 4];
        float4 v2 = *(const float4*)&redY[2][jo][qo][c4 * 4];
        float4 v3 = *(const float4*)&redY[3][jo][qo][c4 * 4];
        yv[c4*4+0] = (v0.x + v1.x + v2.x + v3.x) * inv;
        yv[c4*4+1] = (v0.y + v1.y + v2.y + v3.y) * inv;
        yv[c4*4+2] = (v0.z + v1.z + v2.z + v3.z) * inv;
        yv[c4*4+3] = (v0.w + v1.w + v2.w + v3.w) * inv;
        float4 p0 = *(const float4*)&ly1p[jo][qo][c4 * 4];
        float4 p1 = *(const float4*)&ly1p[2 + jo][qo][c4 * 4];
        y1v[c4*4+0] = (p0.x + p1.x) * inv1;
        y1v[c4*4+1] = (p0.y + p1.y) * inv1;
        y1v[c4*4+2] = (p0.z + p1.z) * inv1;
        y1v[c4*4+3] = (p0.w + p1.w) * inv1;
    }

    int obase = og * 8;
    const float* xb = x   + ((size_t)(b * C_IN + obase)) * N_POS + n;
    float*       ob = out + ((size_t)(b * C_IN + obase)) * N_POS + n;
    #pragma unroll
    for (int o = 0; o < 8; o++) {
        float acc = Wb[obase + o] + Wzb[obase + o] + xb[(size_t)o * N_POS];
        const float4* w4  = (const float4*)(Ww  + (obase + o) * 32);
        const float4* wz4 = (const float4*)(Wzw + (obase + o) * 32);
        #pragma unroll
        for (int c4 = 0; c4 < 8; c4++) {
            float4 a = w4[c4], z = wz4[c4];
            acc += a.x * yv[c4*4+0] + a.y * yv[c4*4+1] + a.z * yv[c4*4+2] + a.w * yv[c4*4+3];
            acc += z.x * y1v[c4*4+0] + z.y * y1v[c4*4+1] + z.z * y1v[c4*4+2] + z.w * y1v[c4*4+3];
        }
        ob[(size_t)o * N_POS] = acc;
    }
}

extern "C" void kernel_launch(void* const* d_in, const int* in_sizes, int n_in,
                              void* d_out, int out_size, void* d_ws, size_t ws_size,
                              hipStream_t stream) {
    const float* x    = (const float*)d_in[0];
    const float* g_w  = (const float*)d_in[1];
    const float* g_b  = (const float*)d_in[2];
    const float* th_w = (const float*)d_in[3];
    const float* th_b = (const float*)d_in[4];
    const float* ph_w = (const float*)d_in[5];
    const float* ph_b = (const float*)d_in[6];
    const float* W_w  = (const float*)d_in[7];
    const float* W_b  = (const float*)d_in[8];
    const float* Wz_w = (const float*)d_in[9];
    const float* Wz_b = (const float*)d_in[10];
    const float* mb   = (const float*)d_in[11];
    float* out = (float*)d_out;

    char* w = (char*)d_ws;
    ushort* tht = (ushort*)w;                        // 2 MB
    ushort* pht = (ushort*)(w + (2u << 20));         // 2 MB
    ushort* gcn = (ushort*)(w + (4u << 20));         // 2 MB
    ushort* mbt = (ushort*)(w + (6u << 20));         // 16 KB
    ushort* mbb = (ushort*)(w + (6u << 20) + 16384); // 16 KB

    proj_kernel<<<dim3(256, 12), 128, 0, stream>>>(x, g_w, g_b, th_w, th_b,
                                                   ph_w, ph_b, mb,
                                                   gcn, tht, pht, mbt, mbb);
    attn_fused<<<512, 512, 0, stream>>>(tht, pht, gcn, mbt, mbb, x,
                                        W_w, W_b, Wz_w, Wz_b, out);
}